// Round 2
// baseline (2671.242 us; speedup 1.0000x reference)
//
#include <hip/hip_runtime.h>
#include <stdint.h>

// Problem constants
#define TS 64
#define BATCH 1024
#define HID 256
#define IMGD 2048

typedef __bf16 bf16_t;
typedef bf16_t bf16x8 __attribute__((ext_vector_type(8)));
typedef float f32x4 __attribute__((ext_vector_type(4)));

// load 8 consecutive fp32 (16B-aligned) and convert to a bf16x8 MFMA fragment
static __device__ __forceinline__ bf16x8 cvt8(const float* __restrict__ p) {
    const f32x4 a = *reinterpret_cast<const f32x4*>(p);
    const f32x4 b = *reinterpret_cast<const f32x4*>(p + 4);
    bf16x8 r;
    r[0] = (bf16_t)a[0]; r[1] = (bf16_t)a[1]; r[2] = (bf16_t)a[2]; r[3] = (bf16_t)a[3];
    r[4] = (bf16_t)b[0]; r[5] = (bf16_t)b[1]; r[6] = (bf16_t)b[2]; r[7] = (bf16_t)b[3];
    return r;
}
static __device__ __forceinline__ uint16_t f2bf(float f) {
    union { float f; uint32_t i; } c; c.f = f;
    uint32_t i = c.i;
    i += 0x7fffu + ((i >> 16) & 1u);   // RNE
    return (uint16_t)(i >> 16);
}
static __device__ __forceinline__ float sigm(float x) { return 1.f / (1.f + __expf(-x)); }
static __device__ __forceinline__ float tanh_f(float x) { return 1.f - 2.f / (1.f + __expf(2.f * x)); }

// ---------------------------------------------------------------------------
// Kernel 1: img = relu(img_feature @ W_img^T + b_img), fp32 out to ws
// M=1024 (batch), N=256, K=2048. Wave tile 16x64, block tile 64x64.
// A-frag: m=lane&15, k=quad*8+j ; B-frag (W_img is [N,K]): n=lane&15, same k.
// C: row(m)=quad*4+reg, col(n)=lane&15.   (m89-verified layout)
// ---------------------------------------------------------------------------
__global__ __launch_bounds__(256, 1) void img_proj_kernel(
    const float* __restrict__ img_feature, const float* __restrict__ W_img,
    const float* __restrict__ b_img, float* __restrict__ img_ws)
{
    const int w = threadIdx.x >> 6, lane = threadIdx.x & 63;
    const int quad = lane >> 4, j = lane & 15;
    const int m0 = blockIdx.x * 64 + w * 16;
    const int n0 = blockIdx.y * 64;

    f32x4 C[4] = {};
    const float* arow = img_feature + (size_t)(m0 + j) * IMGD + quad * 8;
    const float* brow = W_img + (size_t)(n0 + j) * IMGD + quad * 8;
    for (int k = 0; k < IMGD; k += 32) {
        bf16x8 a = cvt8(arow + k);
#pragma unroll
        for (int nt = 0; nt < 4; ++nt) {
            bf16x8 b = cvt8(brow + (size_t)nt * 16 * IMGD + k);
            C[nt] = __builtin_amdgcn_mfma_f32_16x16x32_bf16(a, b, C[nt], 0, 0, 0);
        }
    }
#pragma unroll
    for (int nt = 0; nt < 4; ++nt) {
        int col = n0 + nt * 16 + j;
        float bias = b_img[col];
#pragma unroll
        for (int r = 0; r < 4; ++r) {
            int row = m0 + quad * 4 + r;
            float v = C[nt][r] + bias;
            img_ws[row * HID + col] = v > 0.f ? v : 0.f;
        }
    }
}

// ---------------------------------------------------------------------------
// Kernel 2: persistent fused Embedding + LSTM + broadcast-add.
// 256 blocks x 256 threads. Block (g = blk&63, n = blk>>6):
//   owns batch rows [16g,16g+16) and hidden units [64n,64n+64).
// Wave w owns units uw=64n+16w..+16; its 4 MFMA N-tiles = gates i,f,g,o for
// those units (W rows r=q*256+unit). W_ih/W_hh B-frags persist in registers
// (64 frags = 256 VGPRs, converted fp32->bf16 once). c-state in fp32 regs.
// h exchanged via double-buffered global bf16 + per-group (4-block)
// release/acquire counter per step.
// ---------------------------------------------------------------------------
__global__ __launch_bounds__(256, 1) void lstm_kernel(
    const int* __restrict__ caption, const float* __restrict__ emb,
    const float* __restrict__ W_ih, const float* __restrict__ W_hh,
    const float* __restrict__ b_ih, const float* __restrict__ b_hh,
    const float* __restrict__ img_ws, uint16_t* __restrict__ h_buf,
    unsigned* __restrict__ ctr, float* __restrict__ out)
{
    const int g = blockIdx.x & 63, nchunk = blockIdx.x >> 6;
    const int b0 = g * 16, u0 = nchunk * 64;
    const int w = threadIdx.x >> 6, lane = threadIdx.x & 63;
    const int quad = lane >> 4, j = lane & 15;
    const int uw = u0 + w * 16;   // wave's first unit
    const int unit = uw + j;      // this lane's unit (C/store phase)
    unsigned* myctr = ctr + g * 16;   // one 64B line per group

    // Persistent weight fragments: B-frag n-index = j, k = quad*8.. within k8*32
    bf16x8 Bih[4][8], Bhh[4][8];
#pragma unroll
    for (int q = 0; q < 4; ++q) {
        const int r = q * HID + uw + j;
        const float* pih = W_ih + (size_t)r * HID + quad * 8;
        const float* phh = W_hh + (size_t)r * HID + quad * 8;
#pragma unroll
        for (int k8 = 0; k8 < 8; ++k8) {
            Bih[q][k8] = cvt8(pih + k8 * 32);
            Bhh[q][k8] = cvt8(phh + k8 * 32);
        }
    }
    float bias[4];
#pragma unroll
    for (int q = 0; q < 4; ++q) {
        int r = q * HID + unit;
        bias[q] = b_ih[r] + b_hh[r];
    }
    float imgv[4];
#pragma unroll
    for (int r = 0; r < 4; ++r)
        imgv[r] = img_ws[(b0 + quad * 4 + r) * HID + unit];

    float cst[4] = {0.f, 0.f, 0.f, 0.f};

    // x fragments for t=0 (A-frag row m = lane&15 = j -> batch b0+j)
    bf16x8 Ax[8], Axn[8];
    {
        int cap = caption[b0 + j];
        const float* px = emb + (size_t)cap * HID + quad * 8;
#pragma unroll
        for (int k8 = 0; k8 < 8; ++k8) Ax[k8] = cvt8(px + k8 * 32);
    }

    for (int t = 0; t < TS; ++t) {
        f32x4 C[4];
#pragma unroll
        for (int q = 0; q < 4; ++q) C[q] = (f32x4){bias[q], bias[q], bias[q], bias[q]};

        // x_t @ W_ih^T : independent of h, runs before the sync
#pragma unroll
        for (int k8 = 0; k8 < 8; ++k8) {
#pragma unroll
            for (int q = 0; q < 4; ++q)
                C[q] = __builtin_amdgcn_mfma_f32_16x16x32_bf16(Ax[k8], Bih[q][k8], C[q], 0, 0, 0);
        }

        // prefetch next step's embedding rows (overlaps spin + h-MFMA)
        {
            int tn = (t + 1 < TS) ? t + 1 : t;
            int cap = caption[tn * BATCH + b0 + j];
            const float* px = emb + (size_t)cap * HID + quad * 8;
#pragma unroll
            for (int k8 = 0; k8 < 8; ++k8) Axn[k8] = cvt8(px + k8 * 32);
        }

        if (t > 0) {
            const unsigned target = 4u * (unsigned)t;   // all 4 blocks finished step t-1
            while (__hip_atomic_load(myctr, __ATOMIC_RELAXED, __HIP_MEMORY_SCOPE_AGENT) < target)
                __builtin_amdgcn_s_sleep(1);
            (void)__hip_atomic_load(myctr, __ATOMIC_ACQUIRE, __HIP_MEMORY_SCOPE_AGENT);
            const uint16_t* hb = h_buf + (size_t)((t - 1) & 1) * BATCH * HID
                                       + (size_t)(b0 + j) * HID + quad * 8;
#pragma unroll
            for (int k8 = 0; k8 < 8; ++k8) {
                bf16x8 Ah = __builtin_bit_cast(bf16x8,
                    *reinterpret_cast<const f32x4*>(hb + k8 * 32));
#pragma unroll
                for (int q = 0; q < 4; ++q)
                    C[q] = __builtin_amdgcn_mfma_f32_16x16x32_bf16(Ah, Bhh[q][k8], C[q], 0, 0, 0);
            }
        }

        // LSTM cell elementwise: lane holds gates i,f,g,o for 4 batch rows x 1 unit
        uint16_t* hw = h_buf + (size_t)(t & 1) * BATCH * HID;
#pragma unroll
        for (int r = 0; r < 4; ++r) {
            float ig = sigm(C[0][r]);
            float fg = sigm(C[1][r]);
            float gg = tanh_f(C[2][r]);
            float og = sigm(C[3][r]);
            float c = fg * cst[r] + ig * gg;
            cst[r] = c;
            float h = og * tanh_f(c);
            int row = b0 + quad * 4 + r;
            hw[row * HID + unit] = f2bf(h);
            out[((size_t)t * BATCH + row) * HID + unit] = h + imgv[r];
        }

        // publish h_t to the other 3 blocks of the group
        __threadfence();
        __syncthreads();
        if (threadIdx.x == 0)
            __hip_atomic_fetch_add(myctr, 1u, __ATOMIC_RELEASE, __HIP_MEMORY_SCOPE_AGENT);

#pragma unroll
        for (int k8 = 0; k8 < 8; ++k8) Ax[k8] = Axn[k8];
    }
}

// ---------------------------------------------------------------------------
extern "C" void kernel_launch(void* const* d_in, const int* in_sizes, int n_in,
                              void* d_out, int out_size, void* d_ws, size_t ws_size,
                              hipStream_t stream) {
    const float* img_feature = (const float*)d_in[0];   // [1024, 2048] fp32
    const int*   caption     = (const int*)d_in[1];     // [64, 1024] int32
    const float* W_img       = (const float*)d_in[2];   // [256, 2048] fp32
    const float* b_img       = (const float*)d_in[3];   // [256] fp32
    const float* emb         = (const float*)d_in[4];   // [32000, 256] fp32
    const float* W_ih        = (const float*)d_in[5];   // [1024, 256] fp32
    const float* W_hh        = (const float*)d_in[6];   // [1024, 256] fp32
    const float* b_ih        = (const float*)d_in[7];   // [1024] fp32
    const float* b_hh        = (const float*)d_in[8];   // [1024] fp32
    float* out = (float*)d_out;                         // [64,1024,256] fp32

    uint8_t* ws = (uint8_t*)d_ws;
    unsigned* ctr    = (unsigned*)ws;                          // 64 groups * 64B = 4KB
    float*    img_ws = (float*)(ws + 4096);                    // 1MB fp32 [1024,256]
    uint16_t* h_buf  = (uint16_t*)(ws + 4096 + (1u << 20));    // 2 x [1024,256] bf16 = 1MB

    // ws is poisoned 0xAA before every timed launch: zero the sync counters
    hipMemsetAsync(ctr, 0, 4096, stream);

    img_proj_kernel<<<dim3(16, 4), 256, 0, stream>>>(img_feature, W_img, b_img, img_ws);
    lstm_kernel<<<256, 256, 0, stream>>>(caption, emb, W_ih, W_hh, b_ih, b_hh,
                                         img_ws, h_buf, ctr, out);
}

// Round 3
// 570.663 us; speedup vs baseline: 4.6809x; 4.6809x over previous
//
#include <hip/hip_runtime.h>
#include <stdint.h>

// Problem constants
#define TS 64
#define BATCH 1024
#define HID 256
#define IMGD 2048

typedef __bf16 bf16_t;
typedef bf16_t bf16x8 __attribute__((ext_vector_type(8)));
typedef float f32x4 __attribute__((ext_vector_type(4)));

union U64F2 {
    unsigned long long u[2];
    bf16x8 v;
};

// load 8 consecutive fp32 (16B-aligned) and convert to a bf16x8 MFMA fragment
static __device__ __forceinline__ bf16x8 cvt8(const float* __restrict__ p) {
    const f32x4 a = *reinterpret_cast<const f32x4*>(p);
    const f32x4 b = *reinterpret_cast<const f32x4*>(p + 4);
    bf16x8 r;
    r[0] = (bf16_t)a[0]; r[1] = (bf16_t)a[1]; r[2] = (bf16_t)a[2]; r[3] = (bf16_t)a[3];
    r[4] = (bf16_t)b[0]; r[5] = (bf16_t)b[1]; r[6] = (bf16_t)b[2]; r[7] = (bf16_t)b[3];
    return r;
}
static __device__ __forceinline__ uint16_t f2bf(float f) {
    union { float f; uint32_t i; } c; c.f = f;
    uint32_t i = c.i;
    i += 0x7fffu + ((i >> 16) & 1u);   // RNE
    return (uint16_t)(i >> 16);
}
static __device__ __forceinline__ float sigm(float x) { return 1.f / (1.f + __expf(-x)); }
static __device__ __forceinline__ float tanh_f(float x) { return 1.f - 2.f / (1.f + __expf(2.f * x)); }

// ---------------------------------------------------------------------------
// Kernel 1: img = relu(img_feature @ W_img^T + b_img), fp32 out to ws
// ---------------------------------------------------------------------------
__global__ __launch_bounds__(256, 1) void img_proj_kernel(
    const float* __restrict__ img_feature, const float* __restrict__ W_img,
    const float* __restrict__ b_img, float* __restrict__ img_ws)
{
    const int w = threadIdx.x >> 6, lane = threadIdx.x & 63;
    const int quad = lane >> 4, j = lane & 15;
    const int m0 = blockIdx.x * 64 + w * 16;
    const int n0 = blockIdx.y * 64;

    f32x4 C[4] = {};
    const float* arow = img_feature + (size_t)(m0 + j) * IMGD + quad * 8;
    const float* brow = W_img + (size_t)(n0 + j) * IMGD + quad * 8;
    for (int k = 0; k < IMGD; k += 32) {
        bf16x8 a = cvt8(arow + k);
#pragma unroll
        for (int nt = 0; nt < 4; ++nt) {
            bf16x8 b = cvt8(brow + (size_t)nt * 16 * IMGD + k);
            C[nt] = __builtin_amdgcn_mfma_f32_16x16x32_bf16(a, b, C[nt], 0, 0, 0);
        }
    }
#pragma unroll
    for (int nt = 0; nt < 4; ++nt) {
        int col = n0 + nt * 16 + j;
        float bias = b_img[col];
#pragma unroll
        for (int r = 0; r < 4; ++r) {
            int row = m0 + quad * 4 + r;
            float v = C[nt][r] + bias;
            img_ws[row * HID + col] = v > 0.f ? v : 0.f;
        }
    }
}

// ---------------------------------------------------------------------------
// Kernel 2: persistent fused Embedding + LSTM + broadcast-add.
// 256 blocks x 256 threads. Block (g = blk&63, nchunk = blk>>6):
//   owns batch rows [16g,16g+16) and hidden units [64n,64n+64).
// Weights live in registers/AGPRs (loaded once). c-state in registers.
// h exchange: RELAXED-ONLY agent-scope atomics (no fences -> no buffer_wbl2
// L2 drains). Producer: bf16 h staged in LDS -> packed u64 relaxed atomic
// stores -> __syncthreads (vmcnt drained per wave before s_barrier) ->
// thread0 relaxed fetch_add on group counter. Consumer: relaxed poll, then
// relaxed u64 atomic loads bit-cast into MFMA A-fragments.
// ---------------------------------------------------------------------------
__global__ __launch_bounds__(256, 1) void lstm_kernel(
    const int* __restrict__ caption, const float* __restrict__ emb,
    const float* __restrict__ W_ih, const float* __restrict__ W_hh,
    const float* __restrict__ b_ih, const float* __restrict__ b_hh,
    const float* __restrict__ img_ws, unsigned long long* __restrict__ h_buf64,
    unsigned* __restrict__ ctr, float* __restrict__ out)
{
    __shared__ uint16_t h_lds[16 * 64];   // 2KB: [row_local 0..15][unit_local 0..63]

    const int g = blockIdx.x & 63, nchunk = blockIdx.x >> 6;
    const int b0 = g * 16, u0 = nchunk * 64;
    const int w = threadIdx.x >> 6, lane = threadIdx.x & 63;
    const int quad = lane >> 4, j = lane & 15;
    const int uw = u0 + w * 16;   // wave's first unit
    const int unit = uw + j;      // this lane's unit (C/store phase)
    unsigned* myctr = ctr + g * 16;   // one 64B line per group

    // Persistent weight fragments: B-frag n-index = j, k = quad*8.. within k8*32
    bf16x8 Bih[4][8], Bhh[4][8];
#pragma unroll
    for (int q = 0; q < 4; ++q) {
        const int r = q * HID + uw + j;
        const float* pih = W_ih + (size_t)r * HID + quad * 8;
        const float* phh = W_hh + (size_t)r * HID + quad * 8;
#pragma unroll
        for (int k8 = 0; k8 < 8; ++k8) {
            Bih[q][k8] = cvt8(pih + k8 * 32);
            Bhh[q][k8] = cvt8(phh + k8 * 32);
        }
    }
    float bias[4];
#pragma unroll
    for (int q = 0; q < 4; ++q) {
        int r = q * HID + unit;
        bias[q] = b_ih[r] + b_hh[r];
    }
    float imgv[4];
#pragma unroll
    for (int r = 0; r < 4; ++r)
        imgv[r] = img_ws[(b0 + quad * 4 + r) * HID + unit];

    float cst[4] = {0.f, 0.f, 0.f, 0.f};

    // publish indices: 256 u64 per block-slice; thread i handles u64 #i
    const int prow = threadIdx.x >> 4;        // 0..15 row_local
    const int pcol = threadIdx.x & 15;        // 0..15 u64 within row (4 units each)
    const size_t pub_off = ((size_t)(b0 + prow) * HID + u0 + pcol * 4) >> 2; // u64 index

    // x fragments for t=0 (A-frag row m = lane&15 = j -> batch b0+j)
    bf16x8 Ax[8], Axn[8];
    {
        int cap = caption[b0 + j];
        const float* px = emb + (size_t)cap * HID + quad * 8;
#pragma unroll
        for (int k8 = 0; k8 < 8; ++k8) Ax[k8] = cvt8(px + k8 * 32);
    }

    for (int t = 0; t < TS; ++t) {
        f32x4 C[4];
#pragma unroll
        for (int q = 0; q < 4; ++q) C[q] = (f32x4){bias[q], bias[q], bias[q], bias[q]};

        // x_t @ W_ih^T : independent of h, runs before the sync
#pragma unroll
        for (int k8 = 0; k8 < 8; ++k8) {
#pragma unroll
            for (int q = 0; q < 4; ++q)
                C[q] = __builtin_amdgcn_mfma_f32_16x16x32_bf16(Ax[k8], Bih[q][k8], C[q], 0, 0, 0);
        }

        // prefetch next step's embedding rows (overlaps spin + h-MFMA)
        {
            int tn = (t + 1 < TS) ? t + 1 : t;
            int cap = caption[tn * BATCH + b0 + j];
            const float* px = emb + (size_t)cap * HID + quad * 8;
#pragma unroll
            for (int k8 = 0; k8 < 8; ++k8) Axn[k8] = cvt8(px + k8 * 32);
        }

        if (t > 0) {
            const unsigned target = 4u * (unsigned)t;   // all 4 blocks finished step t-1
            while (__hip_atomic_load(myctr, __ATOMIC_RELAXED, __HIP_MEMORY_SCOPE_AGENT) < target) { }
            const unsigned long long* hb = h_buf64
                + (size_t)((t - 1) & 1) * (BATCH * HID / 4);
            const size_t eoff = ((size_t)(b0 + j) * HID) >> 2;   // u64 index of lane's row
#pragma unroll
            for (int k8 = 0; k8 < 8; ++k8) {
                U64F2 f;
                const unsigned long long* p = hb + eoff + k8 * 8 + quad * 2;
                f.u[0] = __hip_atomic_load(p,     __ATOMIC_RELAXED, __HIP_MEMORY_SCOPE_AGENT);
                f.u[1] = __hip_atomic_load(p + 1, __ATOMIC_RELAXED, __HIP_MEMORY_SCOPE_AGENT);
#pragma unroll
                for (int q = 0; q < 4; ++q)
                    C[q] = __builtin_amdgcn_mfma_f32_16x16x32_bf16(f.v, Bhh[q][k8], C[q], 0, 0, 0);
            }
        }

        // LSTM cell elementwise: lane holds gates i,f,g,o for 4 batch rows x 1 unit
        float hval[4];
#pragma unroll
        for (int r = 0; r < 4; ++r) {
            float ig = sigm(C[0][r]);
            float fg = sigm(C[1][r]);
            float gg = tanh_f(C[2][r]);
            float og = sigm(C[3][r]);
            float c = fg * cst[r] + ig * gg;
            cst[r] = c;
            float h = og * tanh_f(c);
            hval[r] = h;
            h_lds[(quad * 4 + r) * 64 + w * 16 + j] = f2bf(h);
        }

        __syncthreads();   // h_lds complete (also: each wave drains vmcnt)

        // publish packed bf16 h: one relaxed agent-scope u64 atomic store/thread
        {
            unsigned long long vpub =
                reinterpret_cast<const unsigned long long*>(h_lds)[threadIdx.x];
            unsigned long long* hw = h_buf64 + (size_t)(t & 1) * (BATCH * HID / 4);
            __hip_atomic_store(hw + pub_off, vpub, __ATOMIC_RELAXED, __HIP_MEMORY_SCOPE_AGENT);
        }

        __syncthreads();   // every wave drains vmcnt -> all h stores performed
        if (threadIdx.x == 0)
            __hip_atomic_fetch_add(myctr, 1u, __ATOMIC_RELAXED, __HIP_MEMORY_SCOPE_AGENT);

        // out stores off the critical path
#pragma unroll
        for (int r = 0; r < 4; ++r) {
            int row = b0 + quad * 4 + r;
            out[((size_t)t * BATCH + row) * HID + unit] = hval[r] + imgv[r];
        }

#pragma unroll
        for (int k8 = 0; k8 < 8; ++k8) Ax[k8] = Axn[k8];
    }
}

// ---------------------------------------------------------------------------
extern "C" void kernel_launch(void* const* d_in, const int* in_sizes, int n_in,
                              void* d_out, int out_size, void* d_ws, size_t ws_size,
                              hipStream_t stream) {
    const float* img_feature = (const float*)d_in[0];   // [1024, 2048] fp32
    const int*   caption     = (const int*)d_in[1];     // [64, 1024] int32
    const float* W_img       = (const float*)d_in[2];   // [256, 2048] fp32
    const float* b_img       = (const float*)d_in[3];   // [256] fp32
    const float* emb         = (const float*)d_in[4];   // [32000, 256] fp32
    const float* W_ih        = (const float*)d_in[5];   // [1024, 256] fp32
    const float* W_hh        = (const float*)d_in[6];   // [1024, 256] fp32
    const float* b_ih        = (const float*)d_in[7];   // [1024] fp32
    const float* b_hh        = (const float*)d_in[8];   // [1024] fp32
    float* out = (float*)d_out;                         // [64,1024,256] fp32

    uint8_t* ws = (uint8_t*)d_ws;
    unsigned* ctr = (unsigned*)ws;                                  // 64 groups * 64B = 4KB
    float*    img_ws = (float*)(ws + 4096);                         // 1MB fp32 [1024,256]
    unsigned long long* h_buf64 = (unsigned long long*)(ws + 4096 + (1u << 20)); // 2x512KB bf16

    // ws is poisoned 0xAA before every timed launch: zero the sync counters
    hipMemsetAsync(ctr, 0, 4096, stream);

    img_proj_kernel<<<dim3(16, 4), 256, 0, stream>>>(img_feature, W_img, b_img, img_ws);
    lstm_kernel<<<256, 256, 0, stream>>>(caption, emb, W_ih, W_hh, b_ih, b_hh,
                                         img_ws, h_buf64, ctr, out);
}